// Round 5
// baseline (675.306 us; speedup 1.0000x reference)
//
#include <hip/hip_runtime.h>
#include <hip/hip_bf16.h>
#include <float.h>
#include <math.h>

// Shapes fixed by setup_inputs(): B=8, T=4096, C=1024, requested_r=2048.
constexpr int B_ = 8;
constexpr int T_ = 4096;
constexpr int C_ = 1024;
constexpr int K_ = 2048;
constexpr int MROWS = T_ - K_;         // 2048 dropped tokens: only these need argmax

// 256x256 tile, BK=64, 8 waves (2x4), 2-phase schedule (m230/m248: 655-682 TF @ K=1024)
constexpr int BM = 256, BN = 256, BK = 64;
constexpr int NB = K_ / BN;            // 8 n-blocks
constexpr int NKS = C_ / BK;           // 16 K-steps
// fp16 cosine-score noise sigma ~1.4e-5; delta = 4e-4 ~ 20 sigma of gap error.
constexpr float REFINE_DELTA = 4e-4f;

typedef _Float16 f16x8 __attribute__((ext_vector_type(8)));
typedef float    f32x4 __attribute__((ext_vector_type(4)));

__device__ __forceinline__ void gload16(const ushort* g, ushort* l) {
  __builtin_amdgcn_global_load_lds(
      (const __attribute__((address_space(1))) unsigned int*)g,
      (__attribute__((address_space(3))) unsigned int*)l, 16, 0, 0);
}

// ---------------- kernel 0: fused fp16 cast + fp64 squared norm ----------------
// Wave-per-row: no LDS, no block sync; 16 floats/lane, shuffle-reduce only.
__global__ __launch_bounds__(256) void split_score_kernel(
    const float* __restrict__ x, ushort* __restrict__ xh,
    double* __restrict__ sd, float* __restrict__ rnorm)
{
  int lane = threadIdx.x & 63, wave = threadIdx.x >> 6;
  int row = blockIdx.x * 4 + wave;      // b*T + t
  size_t base = (size_t)row * C_;
  double s = 0.0;
  #pragma unroll
  for (int j = 0; j < 4; j++) {
    int i4 = j * 256 + lane * 4;
    float4 v = *reinterpret_cast<const float4*>(&x[base + i4]);
    ushort4 h;
    { _Float16 a = (_Float16)v.x; h.x = *(ushort*)&a; }
    { _Float16 a = (_Float16)v.y; h.y = *(ushort*)&a; }
    { _Float16 a = (_Float16)v.z; h.z = *(ushort*)&a; }
    { _Float16 a = (_Float16)v.w; h.w = *(ushort*)&a; }
    *reinterpret_cast<ushort4*>(&xh[base + i4]) = h;
    s += (double)v.x * v.x + (double)v.y * v.y
       + (double)v.z * v.z + (double)v.w * v.w;
  }
  #pragma unroll
  for (int off = 32; off > 0; off >>= 1) s += __shfl_down(s, off);
  if (lane == 0) {
    sd[row] = s;
    rnorm[row] = (float)(1.0 / (sqrt(s) + 1e-12));
  }
}

// ---------------- kernel 2a: rank-count top-K flags (fp64 keys, exact order) ----
// 16 threads per token (g = tid&15 scans j = jj*16+g: conflict-free stride-16),
// 16 tokens per block -> 2048 blocks (was 256 blocks x 2048-iter serial loops).
__global__ __launch_bounds__(256) void rank_kernel(
    const double* __restrict__ sd, int* __restrict__ flag)
{
  int b = blockIdx.y;
  __shared__ double sh[T_];
  for (int i = threadIdx.x; i < T_; i += 256)
    sh[i] = (i == 0) ? DBL_MAX : sd[b * T_ + i];   // CLS protection
  __syncthreads();
  int tt = threadIdx.x >> 4;           // token within block
  int g  = threadIdx.x & 15;           // scan segment
  int t  = blockIdx.x * 16 + tt;
  double key = sh[t];
  int cnt = 0;
  #pragma unroll 4
  for (int jj = 0; jj < 256; jj++) {
    int j = jj * 16 + g;
    double sj = sh[j];
    cnt += (sj > key) || (sj == key && j < t);     // (score desc, idx asc)
  }
  cnt += __shfl_xor(cnt, 1);
  cnt += __shfl_xor(cnt, 2);
  cnt += __shfl_xor(cnt, 4);
  cnt += __shfl_xor(cnt, 8);
  if (g == 0) flag[b * T_ + t] = (cnt < K_) ? 1 : 0;
}

// ---------------- kernel 2b: prefix over flags -> keep_idx, drop_idx, assign ----
// Also initializes cnt=1 (kept token self-membership) and nref=0 (zero_kernel fused).
__global__ __launch_bounds__(256) void select_kernel(
    const int* __restrict__ flag, int* __restrict__ keep_idx,
    int* __restrict__ drop_idx, int* __restrict__ assign,
    int* __restrict__ cnt, int* __restrict__ nref)
{
  int b = blockIdx.x, tid = threadIdx.x;
  __shared__ int sums[256];
  int f[16], s = 0;
  int base = b * T_ + tid * 16;
  #pragma unroll
  for (int i = 0; i < 16; i++) { f[i] = flag[base + i]; s += f[i]; }
  sums[tid] = s;
  __syncthreads();
  for (int off = 1; off < 256; off <<= 1) {
    int v = 0;
    if (tid >= off) v = sums[tid - off];
    __syncthreads();
    if (tid >= off) sums[tid] += v;
    __syncthreads();
  }
  int run = (tid == 0) ? 0 : sums[tid - 1];
  #pragma unroll
  for (int i = 0; i < 16; i++) {
    int t = tid * 16 + i;
    if (f[i]) { keep_idx[b * K_ + run] = t; assign[b * T_ + t] = run; run++; }
    else drop_idx[b * MROWS + (t - run)] = t;   // t - run = #dropped before t
  }
  #pragma unroll
  for (int i = 0; i < 8; i++) cnt[b * K_ + tid * 8 + i] = 1;
  if (b == 0 && tid == 0) *nref = 0;
}

// ---------------- kernel 3: fp16 MFMA similarity, 256^2 tile, 2-phase ----------
// M compacted to dropped tokens. 8 waves (2Mx4N), each owns a 128x64 sub-tile;
// 64 MFMA per wave per barrier (4x the 128^2 config's amortization).
// LDS 128 KiB: [stage][A/B][kchunk 0..7][row 0..255][8 f16]. 1 block/CU.
// Grid (NB, MROWS/BM, B_), 512 threads.
__global__ __launch_bounds__(512) void mfma_argmax_kernel(
    const ushort* __restrict__ xh, const float* __restrict__ rnorm,
    const int* __restrict__ keep_idx, const int* __restrict__ drop_idx,
    float* __restrict__ pb, float* __restrict__ ps, int* __restrict__ pk)
{
  __shared__ __align__(16) ushort lds[2][2][8][256][8];   // 128 KiB

  int b  = blockIdx.z;
  int m0 = blockIdx.y * BM;
  int n0 = blockIdx.x * BN;
  int tid = threadIdx.x;
  int lane = tid & 63, w = tid >> 6;
  int quad = lane >> 4, col = lane & 15;
  int wm = w >> 2, wn = w & 3;          // wave tile: rows wm*128.., centers wn*64..

  // staging role: wave w stages row-group (w&3)*64+lane, k-chunks (w>>2)*4+{0..3}
  int rg = w & 3;
  int cb = (w >> 2) * 4;
  int srow = rg * 64 + lane;
  int dtok_s = drop_idx[b * MROWS + m0 + srow];
  const ushort* ga = xh + (size_t)(b * T_ + dtok_s) * C_;
  int ktok_s = keep_idx[b * K_ + n0 + srow];
  const ushort* gb = xh + (size_t)(b * T_ + ktok_s) * C_;

  float scale[4]; int ncand[4];
  #pragma unroll
  for (int j = 0; j < 4; j++) {
    int nn = n0 + wn * 64 + j * 16 + col;
    ncand[j] = nn;
    scale[j] = rnorm[b * T_ + keep_idx[b * K_ + nn]];
  }

  f32x4 acc[8][4];
  #pragma unroll
  for (int i = 0; i < 8; i++)
    #pragma unroll
    for (int j = 0; j < 4; j++) acc[i][j] = (f32x4)0.f;

  auto issue = [&](int ks, int st) {
    int k0 = ks * BK;
    #pragma unroll
    for (int c = 0; c < 4; c++) {
      int ch = cb + c;
      gload16(ga + k0 + ch * 8, &lds[st][0][ch][srow][0]);
      gload16(gb + k0 + ch * 8, &lds[st][1][ch][srow][0]);
    }
  };

  issue(0, 0);
  __syncthreads();

  for (int ks = 0; ks < NKS; ks++) {
    int cur = ks & 1;
    if (ks < NKS - 1) issue(ks + 1, cur ^ 1);   // prefetch overlaps compute

    #pragma unroll
    for (int s = 0; s < 2; s++) {               // two k-slices of 32
      f16x8 fb[4];
      #pragma unroll
      for (int j = 0; j < 4; j++)
        fb[j] = *reinterpret_cast<const f16x8*>(
            &lds[cur][1][s * 4 + quad][wn * 64 + j * 16 + col][0]);
      #pragma unroll
      for (int i = 0; i < 8; i++) {
        f16x8 fa = *reinterpret_cast<const f16x8*>(
            &lds[cur][0][s * 4 + quad][wm * 128 + i * 16 + col][0]);
        #pragma unroll
        for (int j = 0; j < 4; j++)
          acc[i][j] = __builtin_amdgcn_mfma_f32_16x16x32_f16(fa, fb[j], acc[i][j], 0, 0, 0);
      }
    }
    __syncthreads();  // drains prefetch (overlapped) + protects buffer swap
  }

  // ---- epilogue: top-2 per token row over this block's 256 centers ----
  float* redb   = (float*)(&lds[0][0][0][0][0]);   // [4][256] overlay on dead LDS
  float* redsec = redb + 1024;
  int*   redk   = (int*)(redb + 2048);

  // C/D layout: col=lane&15 (n), row=quad*4+reg (m)
  #pragma unroll
  for (int i = 0; i < 8; i++) {
    #pragma unroll
    for (int r = 0; r < 4; r++) {
      float b1 = -FLT_MAX, b2 = -FLT_MAX; int k1 = 0;
      #pragma unroll
      for (int j = 0; j < 4; j++) {
        float v = acc[i][j][r] * scale[j];
        if (v > b1) { b2 = b1; b1 = v; k1 = ncand[j]; }
        else if (v > b2) b2 = v;
      }
      #pragma unroll
      for (int off = 1; off < 16; off <<= 1) {
        float ob1 = __shfl_xor(b1, off);
        float ob2 = __shfl_xor(b2, off);
        int   ok1 = __shfl_xor(k1, off);
        if (ob1 > b1 || (ob1 == b1 && ok1 < k1)) { b2 = fmaxf(b1, ob2); b1 = ob1; k1 = ok1; }
        else b2 = fmaxf(b2, ob1);
      }
      if (col == 0) {
        int tl = wm * 128 + i * 16 + quad * 4 + r;
        redb[wn * 256 + tl] = b1; redsec[wn * 256 + tl] = b2; redk[wn * 256 + tl] = k1;
      }
    }
  }
  __syncthreads();
  if (tid < 256) {
    float b1 = redb[tid], b2 = redsec[tid]; int k1 = redk[tid];
    #pragma unroll
    for (int q = 1; q < 4; q++) {      // wn ascending => center ids ascending (ties)
      float o1 = redb[q * 256 + tid], o2 = redsec[q * 256 + tid]; int ok = redk[q * 256 + tid];
      if (o1 > b1) { b2 = fmaxf(b1, o2); b1 = o1; k1 = ok; }
      else b2 = fmaxf(b2, o1);
    }
    size_t p = ((size_t)(b * NB + blockIdx.x)) * MROWS + m0 + tid;
    pb[p] = b1; ps[p] = b2; pk[p] = k1;
  }
}

// ---------------- kernel 3b: merge partials -> assign + count + refine queue ----
// One thread per compacted (dropped) row. Also counts cluster membership.
__global__ __launch_bounds__(256) void reduce2_kernel(
    const float* __restrict__ pb, const float* __restrict__ ps, const int* __restrict__ pk,
    const float* __restrict__ rnorm, const int* __restrict__ drop_idx,
    int* __restrict__ assign, int* __restrict__ cnt,
    int* __restrict__ rlist, int* __restrict__ nref)
{
  int idx2 = blockIdx.x * 256 + threadIdx.x;   // b*MROWS + rc
  int b = idx2 >> 11;                           // MROWS = 2048
  int rc = idx2 & (MROWS - 1);
  float b1 = -FLT_MAX, b2 = -FLT_MAX; int k1 = 0;
  for (int nb = 0; nb < NB; nb++) {            // nb ascending => n ascending
    size_t p = ((size_t)(b * NB + nb)) * MROWS + rc;
    float v = pb[p], s = ps[p]; int k = pk[p];
    if (v > b1) { b2 = fmaxf(b1, s); b1 = v; k1 = k; }
    else b2 = fmaxf(b2, v);
  }
  int t = drop_idx[idx2];
  assign[b * T_ + t] = k1;
  atomicAdd(&cnt[b * K_ + k1], 1);
  if ((b1 - b2) * rnorm[b * T_ + t] < REFINE_DELTA) {
    int qi = atomicAdd(nref, 1);
    rlist[qi] = idx2;
  }
}

// ---------------- kernel 3c: candidate-limited fp64 re-score -------------------
__global__ __launch_bounds__(256) void refine_kernel(
    const float* __restrict__ x, const double* __restrict__ sd,
    const int* __restrict__ keep_idx, const int* __restrict__ drop_idx,
    const float* __restrict__ rnorm,
    const float* __restrict__ pb, const float* __restrict__ ps, const int* __restrict__ pk,
    const int* __restrict__ nref, const int* __restrict__ rlist,
    int* __restrict__ assign, int* __restrict__ cnt)
{
  __shared__ __align__(16) float xs[C_];
  __shared__ int cand[K_];
  __shared__ int ncand_s;
  __shared__ double wv[4];
  __shared__ int wk[4];
  __shared__ float spb[NB], sps[NB];
  __shared__ int spk[NB];
  int n = *nref;
  int lane = threadIdx.x & 63, wave = threadIdx.x >> 6;
  for (int qi = blockIdx.x; qi < n; qi += gridDim.x) {
    int idx2 = rlist[qi];
    int b = idx2 >> 11, rc = idx2 & (MROWS - 1);
    int t = drop_idx[idx2];
    int bt = b * T_ + t;
    __syncthreads();   // protect previous iteration's LDS
    const float* xt = x + ((size_t)b * T_ + t) * C_;
    for (int i = threadIdx.x; i < C_; i += 256) xs[i] = xt[i];
    if (threadIdx.x < NB) {
      size_t p = ((size_t)(b * NB + threadIdx.x)) * MROWS + rc;
      spb[threadIdx.x] = pb[p]; sps[threadIdx.x] = ps[p]; spk[threadIdx.x] = pk[p];
    }
    __syncthreads();
    if (threadIdx.x == 0) {
      float b1 = -FLT_MAX;
      for (int nb = 0; nb < NB; nb++) if (spb[nb] > b1) b1 = spb[nb];
      float thr = b1 - REFINE_DELTA / rnorm[bt];   // cosine delta -> raw score units
      int nc = 0;
      for (int nb = 0; nb < NB; nb++) {
        if (spb[nb] >= thr) {
          if (sps[nb] >= thr) { for (int j = 0; j < BN; j++) cand[nc++] = nb * BN + j; }
          else cand[nc++] = spk[nb];
        }
      }
      ncand_s = nc;
    }
    __syncthreads();
    int nc = ncand_s;
    double bv = -DBL_MAX; int bk = 0x7fffffff;
    for (int ci = wave; ci < nc; ci += 4) {
      int k = cand[ci];
      int kt = keep_idx[b * K_ + k];
      const float* xr = x + ((size_t)b * T_ + kt) * C_;
      double s = 0.0;
      int c0 = lane * 16;
      #pragma unroll
      for (int c = 0; c < 16; c += 4) {
        float4 v = *reinterpret_cast<const float4*>(&xr[c0 + c]);
        s += (double)xs[c0 + c]     * v.x + (double)xs[c0 + c + 1] * v.y
           + (double)xs[c0 + c + 2] * v.z + (double)xs[c0 + c + 3] * v.w;
      }
      #pragma unroll
      for (int off = 32; off > 0; off >>= 1) s += __shfl_down(s, off);
      s = __shfl(s, 0);
      s /= sqrt(sd[b * T_ + kt]);
      if (s > bv || (s == bv && k < bk)) { bv = s; bk = k; }
    }
    if (lane == 0) { wv[wave] = bv; wk[wave] = bk; }
    __syncthreads();
    if (threadIdx.x == 0) {
      double fb = wv[0]; int fk = wk[0];
      for (int w2 = 1; w2 < 4; w2++)
        if (wv[w2] > fb || (wv[w2] == fb && wk[w2] < fk)) { fb = wv[w2]; fk = wk[w2]; }
      int old = assign[bt];
      if (fk != old) {
        atomicSub(&cnt[b * K_ + old], 1);
        atomicAdd(&cnt[b * K_ + fk], 1);
        assign[bt] = fk;
      }
    }
  }
}

// ---------------- kernels 4: counting-sort cluster lists ----------------
__global__ __launch_bounds__(256) void scan_kernel(
    const int* __restrict__ cnt, int* __restrict__ offs, int* __restrict__ cursor)
{
  int b = blockIdx.x, tid = threadIdx.x;
  __shared__ int sums[256];
  int v[8], s = 0;
  int base = b * K_ + tid * 8;
  #pragma unroll
  for (int i = 0; i < 8; i++) { v[i] = cnt[base + i]; s += v[i]; }
  sums[tid] = s;
  __syncthreads();
  for (int off = 1; off < 256; off <<= 1) {
    int t2 = 0;
    if (tid >= off) t2 = sums[tid - off];
    __syncthreads();
    if (tid >= off) sums[tid] += t2;
    __syncthreads();
  }
  int run = (tid == 0) ? 0 : sums[tid - 1];
  #pragma unroll
  for (int i = 0; i < 8; i++) { offs[base + i] = run; cursor[base + i] = run; run += v[i]; }
}

__global__ void scatter_kernel(const int* __restrict__ assign,
                               int* __restrict__ cursor, int* __restrict__ lists)
{
  int i = blockIdx.x * 256 + threadIdx.x;
  int b = i >> 12, t = i & (T_ - 1);
  int p = atomicAdd(&cursor[b * K_ + assign[i]], 1);
  lists[b * T_ + p] = t;
}

// ---------------- kernel 5: segment mean + alpha blend ----------------
__global__ __launch_bounds__(256) void merge_kernel(
    const float* __restrict__ x, const int* __restrict__ keep_idx,
    const int* __restrict__ cnt, const int* __restrict__ offs,
    const int* __restrict__ lists, float* __restrict__ out)
{
  __shared__ int toks[256];
  int b = blockIdx.y, k = blockIdx.x;
  int m = cnt[b * K_ + k], off = offs[b * K_ + k];
  const float* xb = x + (size_t)b * T_ * C_;
  int c4 = threadIdx.x * 4;
  float sx = 0.f, sy = 0.f, sz = 0.f, sw = 0.f;
  for (int basei = 0; basei < m; basei += 256) {
    int nchunk = min(256, m - basei);
    __syncthreads();
    if (threadIdx.x < nchunk) toks[threadIdx.x] = lists[b * T_ + off + basei + threadIdx.x];
    __syncthreads();
    for (int i = 0; i < nchunk; i++) {
      int tok = toks[i];
      float4 v = *reinterpret_cast<const float4*>(&xb[(size_t)tok * C_ + c4]);
      sx += v.x; sy += v.y; sz += v.z; sw += v.w;
    }
  }
  int kt = keep_idx[b * K_ + k];
  float4 xk = *reinterpret_cast<const float4*>(&xb[(size_t)kt * C_ + c4]);
  float fm = (float)m;
  float4 o;
  o.x = 0.85f * xk.x + 0.15f * (sx / fm);
  o.y = 0.85f * xk.y + 0.15f * (sy / fm);
  o.z = 0.85f * xk.z + 0.15f * (sz / fm);
  o.w = 0.85f * xk.w + 0.15f * (sw / fm);
  *reinterpret_cast<float4*>(&out[((size_t)b * K_ + k) * C_ + c4]) = o;
}

// ---------------- launch ----------------
extern "C" void kernel_launch(void* const* d_in, const int* in_sizes, int n_in,
                              void* d_out, int out_size, void* d_ws, size_t ws_size,
                              hipStream_t stream)
{
  const float* x = (const float*)d_in[0];
  float* out = (float*)d_out;

  char* w = (char*)d_ws;
  ushort* xh    = (ushort*)w;  w += sizeof(ushort) * (size_t)B_ * T_ * C_;  // 67 MB
  float* pb     = (float*)w;   w += sizeof(float) * (size_t)B_ * NB * MROWS;
  float* ps     = (float*)w;   w += sizeof(float) * (size_t)B_ * NB * MROWS;
  int*   pk     = (int*)w;     w += sizeof(int) * (size_t)B_ * NB * MROWS;
  double* sd    = (double*)w;  w += sizeof(double) * B_ * T_;
  float* rnorm  = (float*)w;   w += sizeof(float) * B_ * T_;
  int* flag     = (int*)w;     w += sizeof(int) * B_ * T_;
  int* keep_idx = (int*)w;     w += sizeof(int) * B_ * K_;
  int* drop_idx = (int*)w;     w += sizeof(int) * B_ * MROWS;
  int* assign   = (int*)w;     w += sizeof(int) * B_ * T_;
  int* cnt      = (int*)w;     w += sizeof(int) * B_ * K_;
  int* offs     = (int*)w;     w += sizeof(int) * B_ * K_;
  int* cursor   = (int*)w;     w += sizeof(int) * B_ * K_;
  int* lists    = (int*)w;     w += sizeof(int) * B_ * T_;
  int* rlist    = (int*)w;     w += sizeof(int) * B_ * MROWS;
  int* nref     = (int*)w;     w += 256;

  split_score_kernel<<<B_ * T_ / 4, 256, 0, stream>>>(x, xh, sd, rnorm);
  rank_kernel<<<dim3(T_ / 16, B_), 256, 0, stream>>>(sd, flag);
  select_kernel<<<B_, 256, 0, stream>>>(flag, keep_idx, drop_idx, assign, cnt, nref);
  mfma_argmax_kernel<<<dim3(NB, MROWS / BM, B_), 512, 0, stream>>>(
      xh, rnorm, keep_idx, drop_idx, pb, ps, pk);
  reduce2_kernel<<<B_ * MROWS / 256, 256, 0, stream>>>(
      pb, ps, pk, rnorm, drop_idx, assign, cnt, rlist, nref);
  refine_kernel<<<256, 256, 0, stream>>>(
      x, sd, keep_idx, drop_idx, rnorm, pb, ps, pk, nref, rlist, assign, cnt);
  scan_kernel<<<B_, 256, 0, stream>>>(cnt, offs, cursor);
  scatter_kernel<<<B_ * T_ / 256, 256, 0, stream>>>(assign, cursor, lists);
  merge_kernel<<<dim3(K_, B_), 256, 0, stream>>>(x, keep_idx, cnt, offs, lists, out);
}

// Round 7
// 508.144 us; speedup vs baseline: 1.3290x; 1.3290x over previous
//
#include <hip/hip_runtime.h>
#include <hip/hip_bf16.h>
#include <float.h>
#include <math.h>

// Shapes fixed by setup_inputs(): B=8, T=4096, C=1024, requested_r=2048.
constexpr int B_ = 8;
constexpr int T_ = 4096;
constexpr int C_ = 1024;
constexpr int K_ = 2048;
constexpr int MROWS = T_ - K_;         // 2048 dropped tokens: only these need argmax

constexpr int BM = 128, BN = 128, BK = 32;   // round-2 proven config (171.7 us)
constexpr int NB = K_ / BN;            // 16 n-blocks
constexpr int NG = K_ / 64;            // 32 partial groups of 64 centers
// fp16 cosine-score noise sigma ~1.4e-5; delta = 4e-4 ~ 20 sigma of gap error.
constexpr float REFINE_DELTA = 4e-4f;

typedef _Float16 f16x8 __attribute__((ext_vector_type(8)));
typedef float    f32x4 __attribute__((ext_vector_type(4)));

__device__ __forceinline__ void gload16(const ushort* g, ushort* l) {
  __builtin_amdgcn_global_load_lds(
      (const __attribute__((address_space(1))) unsigned int*)g,
      (__attribute__((address_space(3))) unsigned int*)l, 16, 0, 0);
}

// ---------------- kernel 0: fused fp16 cast + fp64 squared norm ----------------
__global__ __launch_bounds__(256) void split_score_kernel(
    const float* __restrict__ x, ushort* __restrict__ xh,
    double* __restrict__ sd, float* __restrict__ rnorm)
{
  int lane = threadIdx.x & 63, wave = threadIdx.x >> 6;
  int row = blockIdx.x * 4 + wave;      // b*T + t
  size_t base = (size_t)row * C_;
  double s = 0.0;
  #pragma unroll
  for (int j = 0; j < 4; j++) {
    int i4 = j * 256 + lane * 4;
    float4 v = *reinterpret_cast<const float4*>(&x[base + i4]);
    ushort4 h;
    { _Float16 a = (_Float16)v.x; h.x = *(ushort*)&a; }
    { _Float16 a = (_Float16)v.y; h.y = *(ushort*)&a; }
    { _Float16 a = (_Float16)v.z; h.z = *(ushort*)&a; }
    { _Float16 a = (_Float16)v.w; h.w = *(ushort*)&a; }
    *reinterpret_cast<ushort4*>(&xh[base + i4]) = h;
    s += (double)v.x * v.x + (double)v.y * v.y
       + (double)v.z * v.z + (double)v.w * v.w;
  }
  #pragma unroll
  for (int off = 32; off > 0; off >>= 1) s += __shfl_down(s, off);
  if (lane == 0) {
    sd[row] = s;
    rnorm[row] = (float)(1.0 / (sqrt(s) + 1e-12));
  }
}

// ---------------- kernel 2a: rank-count top-K flags (fp64 keys, exact order) ----
// 16 threads per token (g = tid&15 scans stride-16), 16 tokens per block.
__global__ __launch_bounds__(256) void rank_kernel(
    const double* __restrict__ sd, int* __restrict__ flag)
{
  int b = blockIdx.y;
  __shared__ double sh[T_];
  for (int i = threadIdx.x; i < T_; i += 256)
    sh[i] = (i == 0) ? DBL_MAX : sd[b * T_ + i];   // CLS protection
  __syncthreads();
  int tt = threadIdx.x >> 4;
  int g  = threadIdx.x & 15;
  int t  = blockIdx.x * 16 + tt;
  double key = sh[t];
  int cnt = 0;
  #pragma unroll 4
  for (int jj = 0; jj < 256; jj++) {
    int j = jj * 16 + g;
    double sj = sh[j];
    cnt += (sj > key) || (sj == key && j < t);     // (score desc, idx asc)
  }
  cnt += __shfl_xor(cnt, 1);
  cnt += __shfl_xor(cnt, 2);
  cnt += __shfl_xor(cnt, 4);
  cnt += __shfl_xor(cnt, 8);
  if (g == 0) flag[b * T_ + t] = (cnt < K_) ? 1 : 0;
}

// ---------------- kernel 2b: prefix over flags -> keep_idx, drop_idx, assign ----
// Also initializes cnt=1 (kept self-membership) and nref=0.
__global__ __launch_bounds__(256) void select_kernel(
    const int* __restrict__ flag, int* __restrict__ keep_idx,
    int* __restrict__ drop_idx, int* __restrict__ assign,
    int* __restrict__ cnt, int* __restrict__ nref)
{
  int b = blockIdx.x, tid = threadIdx.x;
  __shared__ int sums[256];
  int f[16], s = 0;
  int base = b * T_ + tid * 16;
  #pragma unroll
  for (int i = 0; i < 16; i++) { f[i] = flag[base + i]; s += f[i]; }
  sums[tid] = s;
  __syncthreads();
  for (int off = 1; off < 256; off <<= 1) {
    int v = 0;
    if (tid >= off) v = sums[tid - off];
    __syncthreads();
    if (tid >= off) sums[tid] += v;
    __syncthreads();
  }
  int run = (tid == 0) ? 0 : sums[tid - 1];
  #pragma unroll
  for (int i = 0; i < 16; i++) {
    int t = tid * 16 + i;
    if (f[i]) { keep_idx[b * K_ + run] = t; assign[b * T_ + t] = run; run++; }
    else drop_idx[b * MROWS + (t - run)] = t;   // t - run = #dropped before t
  }
  #pragma unroll
  for (int i = 0; i < 8; i++) cnt[b * K_ + tid * 8 + i] = 1;
  if (b == 0 && tid == 0) *nref = 0;
}

// ---------------- kernel 3: fp16 MFMA similarity, double-buffered staging -------
// Round-2 proven structure. Partials now written per 64-center GROUP (g = bx*2+wn)
// directly from the 16-lane top-2 — no cross-wn merge, finer refine granularity.
// Grid (NB, MROWS/BM, B_), 256 threads (4 waves, each a 64x64 sub-tile).
__global__ __launch_bounds__(256) void mfma_argmax_kernel(
    const ushort* __restrict__ xh, const float* __restrict__ rnorm,
    const int* __restrict__ keep_idx, const int* __restrict__ drop_idx,
    float* __restrict__ pb, float* __restrict__ ps, int* __restrict__ pk)
{
  // [stage][A/B][c-chunk 0..3][row 0..127][8 f16] = 32 KiB
  __shared__ __align__(16) ushort lds[2][2][4][128][8];

  int b  = blockIdx.z;
  int m0 = blockIdx.y * BM;
  int n0 = blockIdx.x * BN;
  int tid = threadIdx.x;
  int lane = tid & 63, wave = tid >> 6;
  int quad = lane >> 4, col = lane & 15;
  int wm = wave >> 1, wn = wave & 1;

  int srow = tid & 127;
  int sc8  = (tid >> 7) * 8;   // k-element offset of first staged 16B slot

  int dtok_s = drop_idx[b * MROWS + m0 + srow];
  const ushort* ga = xh + (size_t)(b * T_ + dtok_s) * C_;
  int ktok_s = keep_idx[b * K_ + n0 + srow];
  const ushort* gb = xh + (size_t)(b * T_ + ktok_s) * C_;

  int ldst = tid * 8;          // ushort offset within one [4][128][8] plane

  float scale[4]; int ncand[4];
  #pragma unroll
  for (int j = 0; j < 4; j++) {
    int nn = n0 + wn * 64 + j * 16 + col;
    ncand[j] = nn;
    scale[j] = rnorm[b * T_ + keep_idx[b * K_ + nn]];
  }

  f32x4 acc[4][4];
  #pragma unroll
  for (int i = 0; i < 4; i++)
    #pragma unroll
    for (int j = 0; j < 4; j++) acc[i][j] = (f32x4)0.f;

  auto issue = [&](int k0, int st) {
    ushort* base = &lds[st][0][0][0][0];
    gload16(ga + k0 + sc8,      base + ldst);          // A chunks {0,1}|{2,3}
    gload16(ga + k0 + 16 + sc8, base + ldst + 2048);
    gload16(gb + k0 + sc8,      base + 4096 + ldst);   // B plane
    gload16(gb + k0 + 16 + sc8, base + 4096 + ldst + 2048);
  };

  issue(0, 0);
  __syncthreads();   // vmcnt(0) drain: chunk 0 resident

  for (int ks = 0; ks < C_ / BK; ks++) {
    int cur = ks & 1;
    if (ks < C_ / BK - 1) issue((ks + 1) * BK, cur ^ 1);  // prefetch overlaps compute

    f16x8 fa[4], fb[4];
    #pragma unroll
    for (int i = 0; i < 4; i++) {
      int row = wm * 64 + i * 16 + col;
      fa[i] = *reinterpret_cast<const f16x8*>(&lds[cur][0][quad][row][0]);
    }
    #pragma unroll
    for (int j = 0; j < 4; j++) {
      int row = wn * 64 + j * 16 + col;
      fb[j] = *reinterpret_cast<const f16x8*>(&lds[cur][1][quad][row][0]);
    }
    #pragma unroll
    for (int i = 0; i < 4; i++)
      #pragma unroll
      for (int j = 0; j < 4; j++)
        acc[i][j] = __builtin_amdgcn_mfma_f32_16x16x32_f16(fa[i], fb[j], acc[i][j], 0, 0, 0);
    __syncthreads();  // drains prefetch (overlapped) + protects buffer swap
  }

  // ---- epilogue: top-2 per token row over this wave's 64 centers -> group out --
  // C/D layout: col=lane&15 (n), row=quad*4+reg (m)
  int g = blockIdx.x * 2 + wn;          // 64-center group id in [0, NG)
  #pragma unroll
  for (int i = 0; i < 4; i++) {
    #pragma unroll
    for (int r = 0; r < 4; r++) {
      float b1 = -FLT_MAX, b2 = -FLT_MAX; int k1 = 0;
      #pragma unroll
      for (int j = 0; j < 4; j++) {
        float v = acc[i][j][r] * scale[j];
        if (v > b1) { b2 = b1; b1 = v; k1 = ncand[j]; }
        else if (v > b2) b2 = v;
      }
      #pragma unroll
      for (int off = 1; off < 16; off <<= 1) {
        float ob1 = __shfl_xor(b1, off);
        float ob2 = __shfl_xor(b2, off);
        int   ok1 = __shfl_xor(k1, off);
        if (ob1 > b1 || (ob1 == b1 && ok1 < k1)) { b2 = fmaxf(b1, ob2); b1 = ob1; k1 = ok1; }
        else b2 = fmaxf(b2, ob1);
      }
      if (col == 0) {
        int tl = wm * 64 + i * 16 + quad * 4 + r;
        size_t p = ((size_t)(b * NG + g)) * MROWS + m0 + tl;
        pb[p] = b1; ps[p] = b2; pk[p] = k1;
      }
    }
  }
}

// ---------------- kernel 3b: merge partials -> assign + count + refine queue ----
// One thread per compacted (dropped) row, over NG=32 64-center groups.
__global__ __launch_bounds__(256) void reduce2_kernel(
    const float* __restrict__ pb, const float* __restrict__ ps, const int* __restrict__ pk,
    const float* __restrict__ rnorm, const int* __restrict__ drop_idx,
    int* __restrict__ assign, int* __restrict__ cnt,
    int* __restrict__ rlist, int* __restrict__ nref)
{
  int idx2 = blockIdx.x * 256 + threadIdx.x;   // b*MROWS + rc
  int b = idx2 >> 11;                           // MROWS = 2048
  int rc = idx2 & (MROWS - 1);
  float b1 = -FLT_MAX, b2 = -FLT_MAX; int k1 = 0;
  for (int gg = 0; gg < NG; gg++) {            // g ascending => n ascending
    size_t p = ((size_t)(b * NG + gg)) * MROWS + rc;
    float v = pb[p], s = ps[p]; int k = pk[p];
    if (v > b1) { b2 = fmaxf(b1, s); b1 = v; k1 = k; }
    else b2 = fmaxf(b2, v);
  }
  int t = drop_idx[idx2];
  assign[b * T_ + t] = k1;
  atomicAdd(&cnt[b * K_ + k1], 1);
  if ((b1 - b2) * rnorm[b * T_ + t] < REFINE_DELTA) {
    int qi = atomicAdd(nref, 1);
    rlist[qi] = idx2;
  }
}

// ---------------- kernel 3c: candidate-limited fp64 re-score, wave-per-token ----
// Token row lives in 16 regs/lane (no LDS, no bank conflicts). Per candidate:
// coalesced float4 loads + f64 FMA + 6-step shfl_xor reduce. Group candidates
// at 64 granularity: winner-only unless the group's second-best also clears thr.
__global__ __launch_bounds__(256) void refine_kernel(
    const float* __restrict__ x, const double* __restrict__ sd,
    const int* __restrict__ keep_idx, const int* __restrict__ drop_idx,
    const float* __restrict__ rnorm,
    const float* __restrict__ pb, const float* __restrict__ ps, const int* __restrict__ pk,
    const int* __restrict__ nref, const int* __restrict__ rlist,
    int* __restrict__ assign, int* __restrict__ cnt)
{
  int n = *nref;
  int lane = threadIdx.x & 63;
  int gwave = (blockIdx.x * blockDim.x + threadIdx.x) >> 6;
  int nwaves = (gridDim.x * blockDim.x) >> 6;
  for (int qi = gwave; qi < n; qi += nwaves) {
    int idx2 = rlist[qi];
    int b = idx2 >> 11, rc = idx2 & (MROWS - 1);
    int t = drop_idx[idx2];
    int bt = b * T_ + t;
    const float* xt = x + (size_t)bt * C_;
    // token row into registers: lane owns elements lane*16 .. +15
    const float4* xtv = reinterpret_cast<const float4*>(xt + lane * 16);
    float4 a0 = xtv[0], a1 = xtv[1], a2 = xtv[2], a3 = xtv[3];
    // group partials: lane g < NG holds group g
    float pbg = -FLT_MAX, psg = -FLT_MAX; int pkg = 0;
    if (lane < NG) {
      size_t p = ((size_t)(b * NG + lane)) * MROWS + rc;
      pbg = pb[p]; psg = ps[p]; pkg = pk[p];
    }
    float b1 = pbg;
    #pragma unroll
    for (int off = 32; off > 0; off >>= 1) b1 = fmaxf(b1, __shfl_xor(b1, off));
    float thr = b1 - REFINE_DELTA / rnorm[bt];   // cosine delta -> raw score units

    double bv = -DBL_MAX; int bk = 0x7fffffff;
    for (int g = 0; g < NG; g++) {
      float gpb = __shfl(pbg, g);
      if (gpb < thr) continue;
      float gps = __shfl(psg, g);
      int kfirst, kcount;
      if (gps >= thr) { kfirst = g * 64; kcount = 64; }
      else            { kfirst = __shfl(pkg, g); kcount = 1; }
      for (int jj = 0; jj < kcount; jj++) {
        int k = kfirst + jj;
        int kt = keep_idx[b * K_ + k];
        const float4* xrv = reinterpret_cast<const float4*>(
            x + ((size_t)b * T_ + kt) * C_ + lane * 16);
        float4 v0 = xrv[0], v1 = xrv[1], v2 = xrv[2], v3 = xrv[3];
        double s = (double)a0.x * v0.x + (double)a0.y * v0.y
                 + (double)a0.z * v0.z + (double)a0.w * v0.w
                 + (double)a1.x * v1.x + (double)a1.y * v1.y
                 + (double)a1.z * v1.z + (double)a1.w * v1.w
                 + (double)a2.x * v2.x + (double)a2.y * v2.y
                 + (double)a2.z * v2.z + (double)a2.w * v2.w
                 + (double)a3.x * v3.x + (double)a3.y * v3.y
                 + (double)a3.z * v3.z + (double)a3.w * v3.w;
        #pragma unroll
        for (int off = 32; off > 0; off >>= 1) s += __shfl_xor(s, off);
        s /= sqrt(sd[b * T_ + kt]);              // uniform across lanes
        if (s > bv || (s == bv && k < bk)) { bv = s; bk = k; }
      }
    }
    if (lane == 0) {
      int old = assign[bt];
      if (bk != old) {
        atomicSub(&cnt[b * K_ + old], 1);
        atomicAdd(&cnt[b * K_ + bk], 1);
        assign[bt] = bk;
      }
    }
  }
}

// ---------------- kernels 4: counting-sort cluster lists ----------------
__global__ __launch_bounds__(256) void scan_kernel(
    const int* __restrict__ cnt, int* __restrict__ offs, int* __restrict__ cursor)
{
  int b = blockIdx.x, tid = threadIdx.x;
  __shared__ int sums[256];
  int v[8], s = 0;
  int base = b * K_ + tid * 8;
  #pragma unroll
  for (int i = 0; i < 8; i++) { v[i] = cnt[base + i]; s += v[i]; }
  sums[tid] = s;
  __syncthreads();
  for (int off = 1; off < 256; off <<= 1) {
    int t2 = 0;
    if (tid >= off) t2 = sums[tid - off];
    __syncthreads();
    if (tid >= off) sums[tid] += t2;
    __syncthreads();
  }
  int run = (tid == 0) ? 0 : sums[tid - 1];
  #pragma unroll
  for (int i = 0; i < 8; i++) { offs[base + i] = run; cursor[base + i] = run; run += v[i]; }
}

__global__ void scatter_kernel(const int* __restrict__ assign,
                               int* __restrict__ cursor, int* __restrict__ lists)
{
  int i = blockIdx.x * 256 + threadIdx.x;
  int b = i >> 12, t = i & (T_ - 1);
  int p = atomicAdd(&cursor[b * K_ + assign[i]], 1);
  lists[b * T_ + p] = t;
}

// ---------------- kernel 5: segment mean + alpha blend ----------------
__global__ __launch_bounds__(256) void merge_kernel(
    const float* __restrict__ x, const int* __restrict__ keep_idx,
    const int* __restrict__ cnt, const int* __restrict__ offs,
    const int* __restrict__ lists, float* __restrict__ out)
{
  __shared__ int toks[256];
  int b = blockIdx.y, k = blockIdx.x;
  int m = cnt[b * K_ + k], off = offs[b * K_ + k];
  const float* xb = x + (size_t)b * T_ * C_;
  int c4 = threadIdx.x * 4;
  float sx = 0.f, sy = 0.f, sz = 0.f, sw = 0.f;
  for (int basei = 0; basei < m; basei += 256) {
    int nchunk = min(256, m - basei);
    __syncthreads();
    if (threadIdx.x < nchunk) toks[threadIdx.x] = lists[b * T_ + off + basei + threadIdx.x];
    __syncthreads();
    for (int i = 0; i < nchunk; i++) {
      int tok = toks[i];
      float4 v = *reinterpret_cast<const float4*>(&xb[(size_t)tok * C_ + c4]);
      sx += v.x; sy += v.y; sz += v.z; sw += v.w;
    }
  }
  int kt = keep_idx[b * K_ + k];
  float4 xk = *reinterpret_cast<const float4*>(&xb[(size_t)kt * C_ + c4]);
  float fm = (float)m;
  float4 o;
  o.x = 0.85f * xk.x + 0.15f * (sx / fm);
  o.y = 0.85f * xk.y + 0.15f * (sy / fm);
  o.z = 0.85f * xk.z + 0.15f * (sz / fm);
  o.w = 0.85f * xk.w + 0.15f * (sw / fm);
  *reinterpret_cast<float4*>(&out[((size_t)b * K_ + k) * C_ + c4]) = o;
}

// ---------------- launch ----------------
extern "C" void kernel_launch(void* const* d_in, const int* in_sizes, int n_in,
                              void* d_out, int out_size, void* d_ws, size_t ws_size,
                              hipStream_t stream)
{
  const float* x = (const float*)d_in[0];
  float* out = (float*)d_out;

  char* w = (char*)d_ws;
  ushort* xh    = (ushort*)w;  w += sizeof(ushort) * (size_t)B_ * T_ * C_;  // 67 MB
  float* pb     = (float*)w;   w += sizeof(float) * (size_t)B_ * NG * MROWS; // 2 MB
  float* ps     = (float*)w;   w += sizeof(float) * (size_t)B_ * NG * MROWS;
  int*   pk     = (int*)w;     w += sizeof(int) * (size_t)B_ * NG * MROWS;
  double* sd    = (double*)w;  w += sizeof(double) * B_ * T_;
  float* rnorm  = (float*)w;   w += sizeof(float) * B_ * T_;
  int* flag     = (int*)w;     w += sizeof(int) * B_ * T_;
  int* keep_idx = (int*)w;     w += sizeof(int) * B_ * K_;
  int* drop_idx = (int*)w;     w += sizeof(int) * B_ * MROWS;
  int* assign   = (int*)w;     w += sizeof(int) * B_ * T_;
  int* cnt      = (int*)w;     w += sizeof(int) * B_ * K_;
  int* offs     = (int*)w;     w += sizeof(int) * B_ * K_;
  int* cursor   = (int*)w;     w += sizeof(int) * B_ * K_;
  int* lists    = (int*)w;     w += sizeof(int) * B_ * T_;
  int* rlist    = (int*)w;     w += sizeof(int) * B_ * MROWS;
  int* nref     = (int*)w;     w += 256;

  split_score_kernel<<<B_ * T_ / 4, 256, 0, stream>>>(x, xh, sd, rnorm);
  rank_kernel<<<dim3(T_ / 16, B_), 256, 0, stream>>>(sd, flag);
  select_kernel<<<B_, 256, 0, stream>>>(flag, keep_idx, drop_idx, assign, cnt, nref);
  mfma_argmax_kernel<<<dim3(NB, MROWS / BM, B_), 256, 0, stream>>>(
      xh, rnorm, keep_idx, drop_idx, pb, ps, pk);
  reduce2_kernel<<<B_ * MROWS / 256, 256, 0, stream>>>(
      pb, ps, pk, rnorm, drop_idx, assign, cnt, rlist, nref);
  refine_kernel<<<1024, 256, 0, stream>>>(
      x, sd, keep_idx, drop_idx, rnorm, pb, ps, pk, nref, rlist, assign, cnt);
  scan_kernel<<<B_, 256, 0, stream>>>(cnt, offs, cursor);
  scatter_kernel<<<B_ * T_ / 256, 256, 0, stream>>>(assign, cursor, lists);
  merge_kernel<<<dim3(K_, B_), 256, 0, stream>>>(x, keep_idx, cnt, offs, lists, out);
}